// Round 4
// baseline (427.048 us; speedup 1.0000x reference)
//
#include <hip/hip_runtime.h>
#include <math.h>

// RoPE over x:(B,H,S,D=64) fp32, token_position:(S,) int32.
// One block per token index. All B*H=128 rows at position tok[s] share the
// same 32 (cos,sin) pairs -> compute 2 sincos per thread, reuse over 8 rows.
// Memory-bound: 256 MiB read + 256 MiB write -> ~85 us floor at 6.3 TB/s.

// Native clang vector: legal for __builtin_nontemporal_*, same layout as float4.
typedef float floatx4 __attribute__((ext_vector_type(4)));

// inv_freq[j] = 10000^(-j/32) = 10^(-j/8), correctly-rounded fp32.
__constant__ float kInvFreq[32] = {
    1.0f,                 0.7498942093324559f,   0.5623413251903491f,
    0.4216965034285822f,  0.31622776601683794f,  0.23713737056616552f,
    0.17782794100389229f, 0.13335214321633241f,
    0.1f,                 0.07498942093324559f,  0.05623413251903491f,
    0.04216965034285822f, 0.031622776601683794f, 0.023713737056616552f,
    0.017782794100389229f,0.013335214321633241f,
    0.01f,                0.007498942093324559f, 0.005623413251903491f,
    0.004216965034285822f,0.0031622776601683794f,0.0023713737056616552f,
    0.0017782794100389229f,0.0013335214321633241f,
    0.001f,               0.0007498942093324559f,0.0005623413251903491f,
    0.0004216965034285822f,0.00031622776601683794f,0.00023713737056616552f,
    0.00017782794100389229f,0.00013335214321633241f
};

__global__ __launch_bounds__(256) void rope_fp32_kernel(
    const float* __restrict__ x,
    const int*   __restrict__ tok,
    float*       __restrict__ out,
    int S, int rows_per_group)
{
    const int s_idx = blockIdx.x;
    const int tp    = tok[s_idx];           // position value AND scatter target
    const float pos = (float)tp;

    const int t  = threadIdx.x;
    const int c4 = t & 15;                  // float4 column within 64-elem row
    const int rg = t >> 4;                  // 16 row-groups x rows_per_group rows

    // Two rotation pairs per float4: j0 = 2*c4, j1 = 2*c4+1.
    const float f0 = kInvFreq[2 * c4];
    const float f1 = kInvFreq[2 * c4 + 1];
    float s0, c0, s1, c1;
    // fp32 angle exactly as the reference forms it: fl(pos * inv_freq)
    sincosf(pos * f0, &s0, &c0);            // accurate ocml sincos (PH reduction)
    sincosf(pos * f1, &s1, &c1);

    const floatx4* __restrict__ x4 = (const floatx4*)x;
    floatx4*       __restrict__ o4 = (floatx4*)out;

    // row r in [0, BH): flat addr (in float4 units) = (r*S + tp)*16 + c4
    size_t       base   = ((size_t)(rg * rows_per_group) * (size_t)S + (size_t)tp) * 16 + c4;
    const size_t stride = (size_t)S * 16;

    #pragma unroll 8
    for (int k = 0; k < rows_per_group; ++k) {
        const floatx4 v = __builtin_nontemporal_load(&x4[base]);  // read-once input
        floatx4 r;
        r.x = v.x * c0 - v.y * s0;
        r.y = v.x * s0 + v.y * c0;
        r.z = v.z * c1 - v.w * s1;
        r.w = v.z * s1 + v.w * c1;
        __builtin_nontemporal_store(r, &o4[base]);   // streaming store, skip cache
        base += stride;
    }
}

extern "C" void kernel_launch(void* const* d_in, const int* in_sizes, int n_in,
                              void* d_out, int out_size, void* d_ws, size_t ws_size,
                              hipStream_t stream)
{
    const float* x   = (const float*)d_in[0];
    const int*   tok = (const int*)d_in[1];
    float*       out = (float*)d_out;

    const int S  = in_sizes[1];                 // 8192 token indices
    const int D  = 64;
    const int BH = in_sizes[0] / (S * D);       // 128 rows per position
    const int rows_per_group = BH / 16;         // 8 rows per thread

    rope_fp32_kernel<<<S, 256, 0, stream>>>(x, tok, out, S, rows_per_group);
}